// Round 6
// baseline (827.816 us; speedup 1.0000x reference)
//
#include <hip/hip_runtime.h>

#define H 512
#define W 512
#define TILE 64
#define NT 512
#define SW 104                // LDS row stride in halfs (52 dwords, 20 banks)
#define SROWS 90
#define TPD (W / TILE)        // 8 tiles per dim
// Tile px (y,x) at LDS (13+y, 16+x), fp16. Clamp-replication at true image
// borders self-propagates through the erode chain (validity region shrinks
// 1 px/pass, matching contamination), so no guard refresh is needed.
// Erode pass R writes cols [cs, cs+8G) covering the needed [16-R, 80+R];
// garbage outside never reaches the valid region (radius argument).

typedef _Float16 h8 __attribute__((ext_vector_type(8)));
typedef _Float16 h4 __attribute__((ext_vector_type(4)));

__device__ __forceinline__ float sigmf(float x) {
  return 1.0f / (1.0f + __expf(-x));
}
__device__ __forceinline__ float4 ld4(const float* p) { return *(const float4*)p; }

__device__ __forceinline__ h8 min3v(h8 a, h8 b, h8 c) {
  return __builtin_elementwise_min(__builtin_elementwise_min(a, b), c);
}
__device__ __forceinline__ h8 max3v(h8 a, h8 b, h8 c) {
  return __builtin_elementwise_max(__builtin_elementwise_max(a, b), c);
}
__device__ __forceinline__ h8 shl1(h8 v, _Float16 e) {
  h8 r = __builtin_shufflevector(v, v, 7, 0, 1, 2, 3, 4, 5, 6);
  r[0] = e;
  return r;
}
__device__ __forceinline__ h8 shr1(h8 v, _Float16 e) {
  h8 r = __builtin_shufflevector(v, v, 1, 2, 3, 4, 5, 6, 7, 0);
  r[7] = e;
  return r;
}
__device__ __forceinline__ _Float16 hi_half(const _Float16* p) {
  unsigned v = *(const unsigned*)p;
  return __builtin_bit_cast(_Float16, (unsigned short)(v >> 16));
}
__device__ __forceinline__ _Float16 lo_half(const _Float16* p) {
  unsigned v = *(const unsigned*)p;
  return __builtin_bit_cast(_Float16, (unsigned short)v);
}
__device__ __forceinline__ _Float16 hmax3(_Float16 a, _Float16 b, _Float16 c) {
  _Float16 m = a > b ? a : b;
  return m > c ? m : c;
}
__device__ __forceinline__ unsigned dword_of(h8 v, int i) {
  union { h8 h; unsigned u[4]; } cv;
  cv.h = v;
  return cv.u[i];
}

template <int R>
__device__ __forceinline__ void erode_pass(const _Float16* __restrict__ src,
                                           _Float16* __restrict__ dst, int tid) {
  constexpr int rb = 13 - R;
  constexpr int cs = (15 - R) & ~7;
  constexpr int G = ((80 + R - cs) >> 3) + 1;
  constexpr int ITEMS = (32 + R) * G;
  for (int it = tid; it < ITEMS; it += NT) {
    int rp = it / G;              // constant divisor -> magic mul
    int g = it - rp * G;
    int r0 = rb + 2 * rp;
    const _Float16* s0 = src + (r0 - 1) * SW + cs + 8 * g;
    h8 a = *(const h8*)(s0);
    h8 b = *(const h8*)(s0 + SW);
    h8 c = *(const h8*)(s0 + 2 * SW);
    h8 d = *(const h8*)(s0 + 3 * SW);
    _Float16 le0 = hi_half(s0 + SW - 2);
    _Float16 le1 = hi_half(s0 + 2 * SW - 2);
    _Float16 re0 = lo_half(s0 + SW + 8);
    _Float16 re1 = lo_half(s0 + 2 * SW + 8);
    h8 o0 = __builtin_elementwise_min(
        min3v(a, b, c),
        __builtin_elementwise_min(shl1(b, le0), shr1(b, re0)));
    h8 o1 = __builtin_elementwise_min(
        min3v(b, c, d),
        __builtin_elementwise_min(shl1(c, le1), shr1(c, re1)));
    _Float16* d0 = dst + r0 * SW + cs + 8 * g;
    *(h8*)(d0) = o0;
    *(h8*)(d0 + SW) = o1;
  }
}

// Dilate dst at own 8 px, update skel; returns center row (= next t0).
__device__ __forceinline__ h8 dilate_update(const _Float16* __restrict__ dst,
                                            int rr, int c0, int tg, h8 t0,
                                            h8& skel) {
  const _Float16* pm = dst + (rr - 1) * SW + c0;
  h8 a = *(const h8*)(pm);
  h8 b = *(const h8*)(pm + SW);
  h8 c = *(const h8*)(pm + 2 * SW);
  h8 vm = max3v(a, b, c);
  unsigned nl = __shfl_up((int)dword_of(vm, 3), 1, 8);
  unsigned nr = __shfl_down((int)dword_of(vm, 0), 1, 8);
  _Float16 vl = __builtin_bit_cast(_Float16, (unsigned short)(nl >> 16));
  _Float16 vr = __builtin_bit_cast(_Float16, (unsigned short)nr);
  if (tg == 0) {
    vl = hmax3(hi_half(pm - 2), hi_half(pm + SW - 2), hi_half(pm + 2 * SW - 2));
  }
  if (tg == 7) {
    vr = hmax3(lo_half(pm + 8), lo_half(pm + SW + 8), lo_half(pm + 2 * SW + 8));
  }
  h8 h = max3v(shl1(vm, vl), vm, shr1(vm, vr));
  h8 z = (h8)(_Float16)0.0f;
  h8 d = __builtin_elementwise_max(t0 - h, z);
  skel += __builtin_elementwise_max(d - skel * d, z);
  return b;  // x_{k+1} at own px
}

__global__ __launch_bounds__(NT, 8) void cl_skel_kernel(
    const float* __restrict__ pred, const float* __restrict__ target,
    double* __restrict__ sums, unsigned* __restrict__ counter,
    float* __restrict__ out) {
  __shared__ _Float16 buf0[SROWS * SW];
  __shared__ _Float16 buf1[SROWS * SW];
  __shared__ float rbuf[2][NT / 64];
  __shared__ int lastFlag;

  const int tid = threadIdx.x;
  const int tileIdx = blockIdx.x;
  const int batch = blockIdx.y;
  const bool isPred = (blockIdx.z == 0);
  const int tr = (tileIdx / TPD) * TILE;
  const int tc = (tileIdx % TPD) * TILE;
  const float* __restrict__ img = isPred ? pred : target;
  const float* __restrict__ other = isPred ? target : pred;
  const size_t base = (size_t)batch * (H * W);

  const bool border = (tr == 0) | (tc == 0) | (tr == H - TILE) | (tc == W - TILE);

  // ---- Stage x0 (fp16): rows 0..89, half cols 0..95 (24 h4 groups) ----
  if (!border) {
    for (int it = tid; it < SROWS * 24; it += NT) {
      int row = it / 24, g = it - row * 24;
      int gr = tr - 13 + row;
      int gc = tc - 16 + 4 * g;
      float4 v = ld4(&img[base + (size_t)gr * W + gc]);
      if (isPred) {
        v.x = sigmf(v.x); v.y = sigmf(v.y); v.z = sigmf(v.z); v.w = sigmf(v.w);
      }
      h4 hv;
      hv[0] = (_Float16)v.x; hv[1] = (_Float16)v.y;
      hv[2] = (_Float16)v.z; hv[3] = (_Float16)v.w;
      *(h4*)(buf0 + row * SW + 4 * g) = hv;
    }
  } else {
    for (int it = tid; it < SROWS * 24; it += NT) {
      int row = it / 24, g = it - row * 24;
      int gr = min(max(tr - 13 + row, 0), H - 1);
      int gc = tc - 16 + 4 * g;
      float4 v;
      v.x = img[base + (size_t)gr * W + min(max(gc + 0, 0), W - 1)];
      v.y = img[base + (size_t)gr * W + min(max(gc + 1, 0), W - 1)];
      v.z = img[base + (size_t)gr * W + min(max(gc + 2, 0), W - 1)];
      v.w = img[base + (size_t)gr * W + min(max(gc + 3, 0), W - 1)];
      if (isPred) {
        v.x = sigmf(v.x); v.y = sigmf(v.y); v.z = sigmf(v.z); v.w = sigmf(v.w);
      }
      h4 hv;
      hv[0] = (_Float16)v.x; hv[1] = (_Float16)v.y;
      hv[2] = (_Float16)v.z; hv[3] = (_Float16)v.w;
      *(h4*)(buf0 + row * SW + 4 * g) = hv;
    }
  }
  __syncthreads();

  const int ty = tid >> 3;  // 0..63: own tile row
  const int tg = tid & 7;   // 0..7 : own 8-col group
  const int rr = 13 + ty;
  const int c0 = 16 + 8 * tg;

  h8 skel = (h8)(_Float16)0.0f;
  h8 t0 = *(const h8*)(buf0 + rr * SW + c0);  // x_0 at own px

  // One barrier per iteration: erode reads pre-barrier src + writes dst;
  // dilate (post-barrier) reads only dst; next erode writes old-src (dead).
#define STEP(R, S, D)                          \
  {                                            \
    erode_pass<R>(S, D, tid);                  \
    __syncthreads();                           \
    t0 = dilate_update(D, rr, c0, tg, t0, skel); \
  }
  STEP(11, buf0, buf1)
  STEP(10, buf1, buf0)
  STEP(9, buf0, buf1)
  STEP(8, buf1, buf0)
  STEP(7, buf0, buf1)
  STEP(6, buf1, buf0)
  STEP(5, buf0, buf1)
  STEP(4, buf1, buf0)
  STEP(3, buf0, buf1)
  STEP(2, buf1, buf0)
  STEP(1, buf0, buf1)
#undef STEP

  // ---- Products with the other image over own 8 px ----
  const float* orow = other + base + (size_t)(tr + ty) * W + tc + 8 * tg;
  float s0 = 0.0f, s1 = 0.0f;
#pragma unroll
  for (int q = 0; q < 2; ++q) {
    float4 o = ld4(orow + 4 * q);
    if (!isPred) {
      o.x = sigmf(o.x); o.y = sigmf(o.y); o.z = sigmf(o.z); o.w = sigmf(o.w);
    }
    float sk0 = (float)skel[4 * q + 0], sk1 = (float)skel[4 * q + 1];
    float sk2 = (float)skel[4 * q + 2], sk3 = (float)skel[4 * q + 3];
    s0 += (sk0 + sk1) + (sk2 + sk3);
    s1 += (sk0 * o.x + sk1 * o.y) + (sk2 * o.z + sk3 * o.w);
  }

#pragma unroll
  for (int off = 32; off > 0; off >>= 1) {
    s0 += __shfl_down(s0, off, 64);
    s1 += __shfl_down(s1, off, 64);
  }
  const int wave = tid >> 6;
  if ((tid & 63) == 0) {
    rbuf[0][wave] = s0;
    rbuf[1][wave] = s1;
  }
  __syncthreads();

  const unsigned nblocks = gridDim.x * gridDim.y * gridDim.z;
  if (tid == 0) {
    float t0s = 0.0f, t1s = 0.0f;
#pragma unroll
    for (int w = 0; w < NT / 64; ++w) {
      t0s += rbuf[0][w];
      t1s += rbuf[1][w];
    }
    const int bank = (int)(blockIdx.x & 15);
    const int o2 = (isPred ? 0 : 2);
    atomicAdd(&sums[bank * 16 + o2], (double)t0s);
    atomicAdd(&sums[bank * 16 + o2 + 1], (double)t1s);
    __threadfence();
    unsigned old = atomicAdd(counter, 1u);
    lastFlag = (old == nblocks - 1) ? 1 : 0;
  }
  __syncthreads();

  // ---- Last block reduces the banks and writes the scalar loss ----
  if (lastFlag && tid < 64) {
    __threadfence();
    int b = tid >> 2, j = tid & 3;
    double v = atomicAdd(&sums[b * 16 + j], 0.0);  // device-scope read
#pragma unroll
    for (int off = 4; off < 64; off <<= 1) v += __shfl_down(v, off, 64);
    double s0d = __shfl(v, 0, 64);
    double s1d = __shfl(v, 1, 64);
    double s2d = __shfl(v, 2, 64);
    double s3d = __shfl(v, 3, 64);
    if (tid == 0) {
      double tprec = (s1d + 1.0) / (s0d + 1.0);
      double tsens = (s3d + 1.0) / (s2d + 1.0);
      double cl = 2.0 * tprec * tsens / (tprec + tsens + 1e-7);
      out[0] = (float)(1.0 - cl);
    }
  }
}

extern "C" void kernel_launch(void* const* d_in, const int* in_sizes, int n_in,
                              void* d_out, int out_size, void* d_ws,
                              size_t ws_size, hipStream_t stream) {
  const float* pred = (const float*)d_in[0];
  const float* target = (const float*)d_in[1];
  double* sums = (double*)d_ws;
  unsigned* counter = (unsigned*)((char*)d_ws + 2048);
  const int batch = in_sizes[0] / (H * W);  // 32

  hipMemsetAsync(d_ws, 0, 2048 + 64, stream);
  dim3 grid(TPD * TPD, batch, 2);
  cl_skel_kernel<<<grid, NT, 0, stream>>>(pred, target, sums, counter,
                                          (float*)d_out);
}

// Round 7
// 355.548 us; speedup vs baseline: 2.3283x; 2.3283x over previous
//
#include <hip/hip_runtime.h>

#define H 512
#define W 512
#define TILE 64
#define NT 512
#define SW 104                // LDS row stride in halfs (52 dwords, 20 banks)
#define SROWS 90
#define TPD (W / TILE)        // 8 tiles per dim
// Tile px (y,x) at LDS (13+y, 16+x), fp16. Clamp-replication at true image
// borders self-propagates through the erode chain (validity region shrinks
// 1 px/pass, matching contamination), so no guard refresh is needed.
// NOTE (R6 post-mortem): __launch_bounds__(512,8) forced VGPR=32 -> 2.1 GB
// scratch spill traffic. No min-waves clause: compiler needs ~52 VGPR,
// which already permits 8 waves/EU; LDS (37.9KB, 4 blk/CU) sets occupancy.

typedef _Float16 h8 __attribute__((ext_vector_type(8)));
typedef _Float16 h4 __attribute__((ext_vector_type(4)));

__device__ __forceinline__ float sigmf(float x) {
  return 1.0f / (1.0f + __expf(-x));
}
__device__ __forceinline__ float4 ld4(const float* p) { return *(const float4*)p; }

__device__ __forceinline__ h8 min3v(h8 a, h8 b, h8 c) {
  return __builtin_elementwise_min(__builtin_elementwise_min(a, b), c);
}
__device__ __forceinline__ h8 max3v(h8 a, h8 b, h8 c) {
  return __builtin_elementwise_max(__builtin_elementwise_max(a, b), c);
}
__device__ __forceinline__ h8 shl1(h8 v, _Float16 e) {
  h8 r = __builtin_shufflevector(v, v, 7, 0, 1, 2, 3, 4, 5, 6);
  r[0] = e;
  return r;
}
__device__ __forceinline__ h8 shr1(h8 v, _Float16 e) {
  h8 r = __builtin_shufflevector(v, v, 1, 2, 3, 4, 5, 6, 7, 0);
  r[7] = e;
  return r;
}
__device__ __forceinline__ _Float16 hi_half(const _Float16* p) {
  unsigned v = *(const unsigned*)p;
  return __builtin_bit_cast(_Float16, (unsigned short)(v >> 16));
}
__device__ __forceinline__ _Float16 lo_half(const _Float16* p) {
  unsigned v = *(const unsigned*)p;
  return __builtin_bit_cast(_Float16, (unsigned short)v);
}
__device__ __forceinline__ _Float16 hmax3(_Float16 a, _Float16 b, _Float16 c) {
  _Float16 m = a > b ? a : b;
  return m > c ? m : c;
}
__device__ __forceinline__ unsigned dword_of(h8 v, int i) {
  union { h8 h; unsigned u[4]; } cv;
  cv.h = v;
  return cv.u[i];
}

template <int R>
__device__ __forceinline__ void erode_pass(const _Float16* __restrict__ src,
                                           _Float16* __restrict__ dst, int tid) {
  constexpr int rb = 13 - R;
  constexpr int cs = (15 - R) & ~7;
  constexpr int G = ((80 + R - cs) >> 3) + 1;
  constexpr int ITEMS = (32 + R) * G;
  for (int it = tid; it < ITEMS; it += NT) {
    int rp = it / G;              // constant divisor -> magic mul
    int g = it - rp * G;
    int r0 = rb + 2 * rp;
    const _Float16* s0 = src + (r0 - 1) * SW + cs + 8 * g;
    h8 a = *(const h8*)(s0);
    h8 b = *(const h8*)(s0 + SW);
    h8 c = *(const h8*)(s0 + 2 * SW);
    h8 d = *(const h8*)(s0 + 3 * SW);
    _Float16 le0 = hi_half(s0 + SW - 2);
    _Float16 le1 = hi_half(s0 + 2 * SW - 2);
    _Float16 re0 = lo_half(s0 + SW + 8);
    _Float16 re1 = lo_half(s0 + 2 * SW + 8);
    h8 o0 = __builtin_elementwise_min(
        min3v(a, b, c),
        __builtin_elementwise_min(shl1(b, le0), shr1(b, re0)));
    h8 o1 = __builtin_elementwise_min(
        min3v(b, c, d),
        __builtin_elementwise_min(shl1(c, le1), shr1(c, re1)));
    _Float16* d0 = dst + r0 * SW + cs + 8 * g;
    *(h8*)(d0) = o0;
    *(h8*)(d0 + SW) = o1;
  }
}

// Dilate dst at own 8 px, update skel; returns center row (= next t0).
__device__ __forceinline__ h8 dilate_update(const _Float16* __restrict__ dst,
                                            int rr, int c0, int tg, h8 t0,
                                            h8& skel) {
  const _Float16* pm = dst + (rr - 1) * SW + c0;
  h8 a = *(const h8*)(pm);
  h8 b = *(const h8*)(pm + SW);
  h8 c = *(const h8*)(pm + 2 * SW);
  h8 vm = max3v(a, b, c);
  unsigned nl = __shfl_up((int)dword_of(vm, 3), 1, 8);
  unsigned nr = __shfl_down((int)dword_of(vm, 0), 1, 8);
  _Float16 vl = __builtin_bit_cast(_Float16, (unsigned short)(nl >> 16));
  _Float16 vr = __builtin_bit_cast(_Float16, (unsigned short)nr);
  if (tg == 0) {
    vl = hmax3(hi_half(pm - 2), hi_half(pm + SW - 2), hi_half(pm + 2 * SW - 2));
  }
  if (tg == 7) {
    vr = hmax3(lo_half(pm + 8), lo_half(pm + SW + 8), lo_half(pm + 2 * SW + 8));
  }
  h8 h = max3v(shl1(vm, vl), vm, shr1(vm, vr));
  h8 z = (h8)(_Float16)0.0f;
  h8 d = __builtin_elementwise_max(t0 - h, z);
  skel += __builtin_elementwise_max(d - skel * d, z);
  return b;  // x_{k+1} at own px
}

__global__ __launch_bounds__(NT) void cl_skel_kernel(
    const float* __restrict__ pred, const float* __restrict__ target,
    double* __restrict__ sums, unsigned* __restrict__ counter,
    float* __restrict__ out) {
  __shared__ _Float16 buf0[SROWS * SW];
  __shared__ _Float16 buf1[SROWS * SW];
  __shared__ float rbuf[2][NT / 64];
  __shared__ int lastFlag;

  const int tid = threadIdx.x;
  const int tileIdx = blockIdx.x;
  const int batch = blockIdx.y;
  const bool isPred = (blockIdx.z == 0);
  const int tr = (tileIdx / TPD) * TILE;
  const int tc = (tileIdx % TPD) * TILE;
  const float* __restrict__ img = isPred ? pred : target;
  const float* __restrict__ other = isPred ? target : pred;
  const size_t base = (size_t)batch * (H * W);

  const bool border = (tr == 0) | (tc == 0) | (tr == H - TILE) | (tc == W - TILE);

  // ---- Stage x0 (fp16): rows 0..89, half cols 0..95 (24 h4 groups) ----
  if (!border) {
    for (int it = tid; it < SROWS * 24; it += NT) {
      int row = it / 24, g = it - row * 24;
      int gr = tr - 13 + row;
      int gc = tc - 16 + 4 * g;
      float4 v = ld4(&img[base + (size_t)gr * W + gc]);
      if (isPred) {
        v.x = sigmf(v.x); v.y = sigmf(v.y); v.z = sigmf(v.z); v.w = sigmf(v.w);
      }
      h4 hv;
      hv[0] = (_Float16)v.x; hv[1] = (_Float16)v.y;
      hv[2] = (_Float16)v.z; hv[3] = (_Float16)v.w;
      *(h4*)(buf0 + row * SW + 4 * g) = hv;
    }
  } else {
    for (int it = tid; it < SROWS * 24; it += NT) {
      int row = it / 24, g = it - row * 24;
      int gr = min(max(tr - 13 + row, 0), H - 1);
      int gc = tc - 16 + 4 * g;
      float4 v;
      v.x = img[base + (size_t)gr * W + min(max(gc + 0, 0), W - 1)];
      v.y = img[base + (size_t)gr * W + min(max(gc + 1, 0), W - 1)];
      v.z = img[base + (size_t)gr * W + min(max(gc + 2, 0), W - 1)];
      v.w = img[base + (size_t)gr * W + min(max(gc + 3, 0), W - 1)];
      if (isPred) {
        v.x = sigmf(v.x); v.y = sigmf(v.y); v.z = sigmf(v.z); v.w = sigmf(v.w);
      }
      h4 hv;
      hv[0] = (_Float16)v.x; hv[1] = (_Float16)v.y;
      hv[2] = (_Float16)v.z; hv[3] = (_Float16)v.w;
      *(h4*)(buf0 + row * SW + 4 * g) = hv;
    }
  }
  __syncthreads();

  const int ty = tid >> 3;  // 0..63: own tile row
  const int tg = tid & 7;   // 0..7 : own 8-col group
  const int rr = 13 + ty;
  const int c0 = 16 + 8 * tg;

  h8 skel = (h8)(_Float16)0.0f;
  h8 t0 = *(const h8*)(buf0 + rr * SW + c0);  // x_0 at own px

  // One barrier per iteration: erode reads pre-barrier src + writes dst;
  // dilate (post-barrier) reads only dst; next erode writes old-src (dead).
#define STEP(R, S, D)                          \
  {                                            \
    erode_pass<R>(S, D, tid);                  \
    __syncthreads();                           \
    t0 = dilate_update(D, rr, c0, tg, t0, skel); \
  }
  STEP(11, buf0, buf1)
  STEP(10, buf1, buf0)
  STEP(9, buf0, buf1)
  STEP(8, buf1, buf0)
  STEP(7, buf0, buf1)
  STEP(6, buf1, buf0)
  STEP(5, buf0, buf1)
  STEP(4, buf1, buf0)
  STEP(3, buf0, buf1)
  STEP(2, buf1, buf0)
  STEP(1, buf0, buf1)
#undef STEP

  // ---- Products with the other image over own 8 px ----
  const float* orow = other + base + (size_t)(tr + ty) * W + tc + 8 * tg;
  float s0 = 0.0f, s1 = 0.0f;
#pragma unroll
  for (int q = 0; q < 2; ++q) {
    float4 o = ld4(orow + 4 * q);
    if (!isPred) {
      o.x = sigmf(o.x); o.y = sigmf(o.y); o.z = sigmf(o.z); o.w = sigmf(o.w);
    }
    float sk0 = (float)skel[4 * q + 0], sk1 = (float)skel[4 * q + 1];
    float sk2 = (float)skel[4 * q + 2], sk3 = (float)skel[4 * q + 3];
    s0 += (sk0 + sk1) + (sk2 + sk3);
    s1 += (sk0 * o.x + sk1 * o.y) + (sk2 * o.z + sk3 * o.w);
  }

#pragma unroll
  for (int off = 32; off > 0; off >>= 1) {
    s0 += __shfl_down(s0, off, 64);
    s1 += __shfl_down(s1, off, 64);
  }
  const int wave = tid >> 6;
  if ((tid & 63) == 0) {
    rbuf[0][wave] = s0;
    rbuf[1][wave] = s1;
  }
  __syncthreads();

  const unsigned nblocks = gridDim.x * gridDim.y * gridDim.z;
  if (tid == 0) {
    float t0s = 0.0f, t1s = 0.0f;
#pragma unroll
    for (int w = 0; w < NT / 64; ++w) {
      t0s += rbuf[0][w];
      t1s += rbuf[1][w];
    }
    const int bank = (int)(blockIdx.x & 15);
    const int o2 = (isPred ? 0 : 2);
    atomicAdd(&sums[bank * 16 + o2], (double)t0s);
    atomicAdd(&sums[bank * 16 + o2 + 1], (double)t1s);
    __threadfence();
    unsigned old = atomicAdd(counter, 1u);
    lastFlag = (old == nblocks - 1) ? 1 : 0;
  }
  __syncthreads();

  // ---- Last block reduces the banks and writes the scalar loss ----
  if (lastFlag && tid < 64) {
    __threadfence();
    int b = tid >> 2, j = tid & 3;
    double v = atomicAdd(&sums[b * 16 + j], 0.0);  // device-scope read
#pragma unroll
    for (int off = 4; off < 64; off <<= 1) v += __shfl_down(v, off, 64);
    double s0d = __shfl(v, 0, 64);
    double s1d = __shfl(v, 1, 64);
    double s2d = __shfl(v, 2, 64);
    double s3d = __shfl(v, 3, 64);
    if (tid == 0) {
      double tprec = (s1d + 1.0) / (s0d + 1.0);
      double tsens = (s3d + 1.0) / (s2d + 1.0);
      double cl = 2.0 * tprec * tsens / (tprec + tsens + 1e-7);
      out[0] = (float)(1.0 - cl);
    }
  }
}

extern "C" void kernel_launch(void* const* d_in, const int* in_sizes, int n_in,
                              void* d_out, int out_size, void* d_ws,
                              size_t ws_size, hipStream_t stream) {
  const float* pred = (const float*)d_in[0];
  const float* target = (const float*)d_in[1];
  double* sums = (double*)d_ws;
  unsigned* counter = (unsigned*)((char*)d_ws + 2048);
  const int batch = in_sizes[0] / (H * W);  // 32

  hipMemsetAsync(d_ws, 0, 2048 + 64, stream);
  dim3 grid(TPD * TPD, batch, 2);
  cl_skel_kernel<<<grid, NT, 0, stream>>>(pred, target, sums, counter,
                                          (float*)d_out);
}

// Round 8
// 262.424 us; speedup vs baseline: 3.1545x; 1.3549x over previous
//
#include <hip/hip_runtime.h>

#define H 512
#define W 512
#define TILE 64
#define NT 256
#define SW 104                // LDS row stride in halfs (52 dwords)
#define SROWS 90
#define TPD (W / TILE)        // 8 tiles per dim
// Tile px (y,x) at LDS (13+y, 16+x), fp16. Clamp-replication at true image
// borders self-propagates through the erode chain (validity region shrinks
// 1 px/pass), so no guard refresh is needed.
// R8 notes: NT=256 (1 wave/EU granularity: VGPR-safe up to 128 at 4 blk/CU,
// the LDS cap). t0 carried from dilate center row. Erode cols narrowed:
// R>=8: cs=0,G=12; R<=7: cs=8,G=10 (stale cols land outside needed region).

typedef _Float16 h8 __attribute__((ext_vector_type(8)));
typedef _Float16 h4 __attribute__((ext_vector_type(4)));

__device__ __forceinline__ float sigmf(float x) {
  return 1.0f / (1.0f + __expf(-x));
}
__device__ __forceinline__ float4 ld4(const float* p) { return *(const float4*)p; }

__device__ __forceinline__ h8 min3v(h8 a, h8 b, h8 c) {
  return __builtin_elementwise_min(__builtin_elementwise_min(a, b), c);
}
__device__ __forceinline__ h8 max3v(h8 a, h8 b, h8 c) {
  return __builtin_elementwise_max(__builtin_elementwise_max(a, b), c);
}
__device__ __forceinline__ h8 shl1(h8 v, _Float16 e) {
  h8 r = __builtin_shufflevector(v, v, 7, 0, 1, 2, 3, 4, 5, 6);
  r[0] = e;
  return r;
}
__device__ __forceinline__ h8 shr1(h8 v, _Float16 e) {
  h8 r = __builtin_shufflevector(v, v, 1, 2, 3, 4, 5, 6, 7, 0);
  r[7] = e;
  return r;
}
__device__ __forceinline__ _Float16 hi_half(const _Float16* p) {
  unsigned v = *(const unsigned*)p;
  return __builtin_bit_cast(_Float16, (unsigned short)(v >> 16));
}
__device__ __forceinline__ _Float16 lo_half(const _Float16* p) {
  unsigned v = *(const unsigned*)p;
  return __builtin_bit_cast(_Float16, (unsigned short)v);
}
__device__ __forceinline__ _Float16 hmax3(_Float16 a, _Float16 b, _Float16 c) {
  _Float16 m = a > b ? a : b;
  return m > c ? m : c;
}

// Erode src->dst, rows [13-R, 76+R] as row pairs, cols [CS, CS+8G).
template <int CS, int G>
__device__ __forceinline__ void erode_g(const _Float16* __restrict__ src,
                                        _Float16* __restrict__ dst, int R,
                                        int tid) {
  const int rb = 13 - R;
  const int items = (32 + R) * G;
  for (int it = tid; it < items; it += NT) {
    int rp = it / G;  // G is constexpr -> magic mul
    int g = it - rp * G;
    int r0 = rb + 2 * rp;
    const _Float16* s0 = src + (r0 - 1) * SW + CS + 8 * g;
    h8 a = *(const h8*)(s0);
    h8 b = *(const h8*)(s0 + SW);
    h8 c = *(const h8*)(s0 + 2 * SW);
    h8 d = *(const h8*)(s0 + 3 * SW);
    _Float16 le0 = hi_half(s0 + SW - 2);
    _Float16 le1 = hi_half(s0 + 2 * SW - 2);
    _Float16 re0 = lo_half(s0 + SW + 8);
    _Float16 re1 = lo_half(s0 + 2 * SW + 8);
    h8 o0 = __builtin_elementwise_min(
        min3v(a, b, c),
        __builtin_elementwise_min(shl1(b, le0), shr1(b, re0)));
    h8 o1 = __builtin_elementwise_min(
        min3v(b, c, d),
        __builtin_elementwise_min(shl1(c, le1), shr1(c, re1)));
    _Float16* d0 = dst + r0 * SW + CS + 8 * g;
    *(h8*)(d0) = o0;
    *(h8*)(d0 + SW) = o1;
  }
}

__global__ __launch_bounds__(NT) void cl_skel_kernel(
    const float* __restrict__ pred, const float* __restrict__ target,
    double* __restrict__ sums, unsigned* __restrict__ counter,
    float* __restrict__ out) {
  __shared__ _Float16 buf0[SROWS * SW];
  __shared__ _Float16 buf1[SROWS * SW];
  __shared__ float rbuf[2][NT / 64];
  __shared__ int lastFlag;

  const int tid = threadIdx.x;
  const int tileIdx = blockIdx.x;
  const int batch = blockIdx.y;
  const bool isPred = (blockIdx.z == 0);
  const int tr = (tileIdx / TPD) * TILE;
  const int tc = (tileIdx % TPD) * TILE;
  const float* __restrict__ img = isPred ? pred : target;
  const float* __restrict__ other = isPred ? target : pred;
  const size_t base = (size_t)batch * (H * W);

  const bool border = (tr == 0) | (tc == 0) | (tr == H - TILE) | (tc == W - TILE);

  // ---- Stage x0 (fp16): rows 0..89, half cols 0..95 (24 h4 groups) ----
  if (!border) {
    for (int it = tid; it < SROWS * 24; it += NT) {
      int row = it / 24, g = it - row * 24;
      int gr = tr - 13 + row;
      int gc = tc - 16 + 4 * g;
      float4 v = ld4(&img[base + (size_t)gr * W + gc]);
      if (isPred) {
        v.x = sigmf(v.x); v.y = sigmf(v.y); v.z = sigmf(v.z); v.w = sigmf(v.w);
      }
      h4 hv;
      hv[0] = (_Float16)v.x; hv[1] = (_Float16)v.y;
      hv[2] = (_Float16)v.z; hv[3] = (_Float16)v.w;
      *(h4*)(buf0 + row * SW + 4 * g) = hv;
    }
  } else {
    for (int it = tid; it < SROWS * 24; it += NT) {
      int row = it / 24, g = it - row * 24;
      int gr = min(max(tr - 13 + row, 0), H - 1);
      int gc = tc - 16 + 4 * g;
      float4 v;
      v.x = img[base + (size_t)gr * W + min(max(gc + 0, 0), W - 1)];
      v.y = img[base + (size_t)gr * W + min(max(gc + 1, 0), W - 1)];
      v.z = img[base + (size_t)gr * W + min(max(gc + 2, 0), W - 1)];
      v.w = img[base + (size_t)gr * W + min(max(gc + 3, 0), W - 1)];
      if (isPred) {
        v.x = sigmf(v.x); v.y = sigmf(v.y); v.z = sigmf(v.z); v.w = sigmf(v.w);
      }
      h4 hv;
      hv[0] = (_Float16)v.x; hv[1] = (_Float16)v.y;
      hv[2] = (_Float16)v.z; hv[3] = (_Float16)v.w;
      *(h4*)(buf0 + row * SW + 4 * g) = hv;
    }
  }
  __syncthreads();

  const int ty = tid >> 2;  // 0..63: own tile row
  const int tg = tid & 3;   // 0..3 : own 16-col group
  const int rr = 13 + ty;
  const int c0 = 16 + 16 * tg;

  h8 skelE = (h8)(_Float16)0.0f;
  h8 skelF = (h8)(_Float16)0.0f;
  // t0 = x_0 at own 16 px; thereafter carried from dilate's center row.
  h8 t0E = *(const h8*)(buf0 + rr * SW + c0);
  h8 t0F = *(const h8*)(buf0 + rr * SW + c0 + 8);

  _Float16* src = buf0;
  _Float16* dst = buf1;

#pragma unroll 1
  for (int R = 11; R >= 1; --R) {
    if (R >= 8) erode_g<0, 12>(src, dst, R, tid);
    else        erode_g<8, 10>(src, dst, R, tid);
    __syncthreads();

    // ---- dilate(dst) at own 16 px; skel update; carry center row ----
    {
      const _Float16* pm = dst + (rr - 1) * SW + c0;
      h8 aE = *(const h8*)(pm),          aF = *(const h8*)(pm + 8);
      h8 bE = *(const h8*)(pm + SW),     bF = *(const h8*)(pm + SW + 8);
      h8 cE = *(const h8*)(pm + 2 * SW), cF = *(const h8*)(pm + 2 * SW + 8);
      _Float16 vl = hmax3(hi_half(pm - 2), hi_half(pm + SW - 2),
                          hi_half(pm + 2 * SW - 2));
      _Float16 vr = hmax3(lo_half(pm + 16), lo_half(pm + SW + 16),
                          lo_half(pm + 2 * SW + 16));
      h8 vmE = max3v(aE, bE, cE);
      h8 vmF = max3v(aF, bF, cF);
      h8 hE = max3v(shl1(vmE, vl), vmE, shr1(vmE, vmF[0]));
      h8 hF = max3v(shl1(vmF, vmE[7]), vmF, shr1(vmF, vr));
      h8 z = (h8)(_Float16)0.0f;
      h8 dE = __builtin_elementwise_max(t0E - hE, z);
      h8 dF = __builtin_elementwise_max(t0F - hF, z);
      skelE += __builtin_elementwise_max(dE - skelE * dE, z);
      skelF += __builtin_elementwise_max(dF - skelF * dF, z);
      t0E = bE;  // x_{k+1} at own px
      t0F = bF;
    }
    _Float16* t = src; src = dst; dst = t;
    // single barrier/iter: next erode writes old-src, whose last readers
    // (previous erode) finished before this barrier.
  }

  // ---- Products with the other image over own 16 px ----
  const float* orow = other + base + (size_t)(tr + ty) * W + tc + 16 * tg;
  float s0 = 0.0f, s1 = 0.0f;
#pragma unroll
  for (int q = 0; q < 4; ++q) {
    float4 o = ld4(orow + 4 * q);
    if (!isPred) {
      o.x = sigmf(o.x); o.y = sigmf(o.y); o.z = sigmf(o.z); o.w = sigmf(o.w);
    }
    float sk0, sk1, sk2, sk3;
    if (q < 2) {
      sk0 = (float)skelE[4 * q + 0]; sk1 = (float)skelE[4 * q + 1];
      sk2 = (float)skelE[4 * q + 2]; sk3 = (float)skelE[4 * q + 3];
    } else {
      sk0 = (float)skelF[4 * q - 8]; sk1 = (float)skelF[4 * q - 7];
      sk2 = (float)skelF[4 * q - 6]; sk3 = (float)skelF[4 * q - 5];
    }
    s0 += (sk0 + sk1) + (sk2 + sk3);
    s1 += (sk0 * o.x + sk1 * o.y) + (sk2 * o.z + sk3 * o.w);
  }

#pragma unroll
  for (int off = 32; off > 0; off >>= 1) {
    s0 += __shfl_down(s0, off, 64);
    s1 += __shfl_down(s1, off, 64);
  }
  const int wave = tid >> 6;
  if ((tid & 63) == 0) {
    rbuf[0][wave] = s0;
    rbuf[1][wave] = s1;
  }
  __syncthreads();

  const unsigned nblocks = gridDim.x * gridDim.y * gridDim.z;
  if (tid == 0) {
    float t0s = 0.0f, t1s = 0.0f;
#pragma unroll
    for (int w = 0; w < NT / 64; ++w) {
      t0s += rbuf[0][w];
      t1s += rbuf[1][w];
    }
    const int bank = (int)(blockIdx.x & 15);
    const int o2 = (isPred ? 0 : 2);
    atomicAdd(&sums[bank * 16 + o2], (double)t0s);
    atomicAdd(&sums[bank * 16 + o2 + 1], (double)t1s);
    __threadfence();
    unsigned old = atomicAdd(counter, 1u);
    lastFlag = (old == nblocks - 1) ? 1 : 0;
  }
  __syncthreads();

  // ---- Last block reduces the banks and writes the scalar loss ----
  if (lastFlag && tid < 64) {
    __threadfence();
    int b = tid >> 2, j = tid & 3;
    double v = atomicAdd(&sums[b * 16 + j], 0.0);  // device-scope read
#pragma unroll
    for (int off = 4; off < 64; off <<= 1) v += __shfl_down(v, off, 64);
    double s0d = __shfl(v, 0, 64);
    double s1d = __shfl(v, 1, 64);
    double s2d = __shfl(v, 2, 64);
    double s3d = __shfl(v, 3, 64);
    if (tid == 0) {
      double tprec = (s1d + 1.0) / (s0d + 1.0);
      double tsens = (s3d + 1.0) / (s2d + 1.0);
      double cl = 2.0 * tprec * tsens / (tprec + tsens + 1e-7);
      out[0] = (float)(1.0 - cl);
    }
  }
}

extern "C" void kernel_launch(void* const* d_in, const int* in_sizes, int n_in,
                              void* d_out, int out_size, void* d_ws,
                              size_t ws_size, hipStream_t stream) {
  const float* pred = (const float*)d_in[0];
  const float* target = (const float*)d_in[1];
  double* sums = (double*)d_ws;
  unsigned* counter = (unsigned*)((char*)d_ws + 2048);
  const int batch = in_sizes[0] / (H * W);  // 32

  hipMemsetAsync(d_ws, 0, 2048 + 64, stream);
  dim3 grid(TPD * TPD, batch, 2);
  cl_skel_kernel<<<grid, NT, 0, stream>>>(pred, target, sums, counter,
                                          (float*)d_out);
}

// Round 9
// 227.552 us; speedup vs baseline: 3.6379x; 1.1532x over previous
//
#include <hip/hip_runtime.h>

#define H 512
#define W 512
#define TILE 64
#define NT 256
#define SW 104                // LDS row stride in halfs (52 dwords)
#define SROWS 90
#define TPD (W / TILE)        // 8 tiles per dim
#define NBANKS 16
#define BANK_STRIDE 16
// Tile px (y,x) at LDS (13+y, 16+x), fp16. Clamp-replication at true image
// borders self-propagates (r5-proven). R9: erode region FIXED at rows [2,87]
// x cols [0,96) for every pass -> per-thread item addresses are pass-invariant
// (computed once); pass-pair unroll makes buf0/buf1 literals so the buffer
// toggle folds into ds immediate offsets. Bitwise-equivalent to r5 in the
// dilate-visible region (rows 12..77): garbage from buf1's unwritten rows
// 0,1,88,89 advances 1 row/pass, always exactly outside the needed range.

typedef _Float16 h8 __attribute__((ext_vector_type(8)));
typedef _Float16 h4 __attribute__((ext_vector_type(4)));

__device__ __forceinline__ float sigmf(float x) {
  return 1.0f / (1.0f + __expf(-x));
}
__device__ __forceinline__ float4 ld4(const float* p) { return *(const float4*)p; }

__device__ __forceinline__ h8 min3v(h8 a, h8 b, h8 c) {
  return __builtin_elementwise_min(__builtin_elementwise_min(a, b), c);
}
__device__ __forceinline__ h8 max3v(h8 a, h8 b, h8 c) {
  return __builtin_elementwise_max(__builtin_elementwise_max(a, b), c);
}
__device__ __forceinline__ h8 shl1(h8 v, _Float16 e) {
  h8 r = __builtin_shufflevector(v, v, 7, 0, 1, 2, 3, 4, 5, 6);
  r[0] = e;
  return r;
}
__device__ __forceinline__ h8 shr1(h8 v, _Float16 e) {
  h8 r = __builtin_shufflevector(v, v, 1, 2, 3, 4, 5, 6, 7, 0);
  r[7] = e;
  return r;
}
__device__ __forceinline__ _Float16 hi_half(const _Float16* p) {
  unsigned v = *(const unsigned*)p;
  return __builtin_bit_cast(_Float16, (unsigned short)(v >> 16));
}
__device__ __forceinline__ _Float16 lo_half(const _Float16* p) {
  unsigned v = *(const unsigned*)p;
  return __builtin_bit_cast(_Float16, (unsigned short)v);
}
__device__ __forceinline__ _Float16 hmax3(_Float16 a, _Float16 b, _Float16 c) {
  _Float16 m = a > b ? a : b;
  return m > c ? m : c;
}

// One erode item at half-index a = r0*SW + 8*g: rows r0,r0+1 from rows
// r0-1..r0+2, cols 8g..8g+7. a is pass-invariant; src/dst are LDS literals.
__device__ __forceinline__ void erode_item(const _Float16* __restrict__ src,
                                           _Float16* __restrict__ dst, int a) {
  h8 A = *(const h8*)(src + a - SW);
  h8 B = *(const h8*)(src + a);
  h8 C = *(const h8*)(src + a + SW);
  h8 D = *(const h8*)(src + a + 2 * SW);
  _Float16 le0 = hi_half(src + a - 2);
  _Float16 re0 = lo_half(src + a + 8);
  _Float16 le1 = hi_half(src + a + SW - 2);
  _Float16 re1 = lo_half(src + a + SW + 8);
  h8 o0 = __builtin_elementwise_min(
      min3v(A, B, C),
      __builtin_elementwise_min(shl1(B, le0), shr1(B, re0)));
  h8 o1 = __builtin_elementwise_min(
      min3v(B, C, D),
      __builtin_elementwise_min(shl1(C, le1), shr1(C, re1)));
  *(h8*)(dst + a) = o0;
  *(h8*)(dst + a + SW) = o1;
}

__global__ __launch_bounds__(NT) void cl_skel_kernel(
    const float* __restrict__ pred, const float* __restrict__ target,
    double* __restrict__ sums) {
  __shared__ _Float16 buf0[SROWS * SW];
  __shared__ _Float16 buf1[SROWS * SW];
  __shared__ float rbuf[2][NT / 64];

  const int tid = threadIdx.x;
  const int tileIdx = blockIdx.x;
  const int batch = blockIdx.y;
  const bool isPred = (blockIdx.z == 0);
  const int tr = (tileIdx / TPD) * TILE;
  const int tc = (tileIdx % TPD) * TILE;
  const float* __restrict__ img = isPred ? pred : target;
  const float* __restrict__ other = isPred ? target : pred;
  const size_t base = (size_t)batch * (H * W);

  const bool border = (tr == 0) | (tc == 0) | (tr == H - TILE) | (tc == W - TILE);

  // ---- Stage x0 (fp16): rows 0..89, half cols 0..95 (24 h4 groups) ----
  if (!border) {
    for (int it = tid; it < SROWS * 24; it += NT) {
      int row = it / 24, g = it - row * 24;
      int gr = tr - 13 + row;
      int gc = tc - 16 + 4 * g;
      float4 v = ld4(&img[base + (size_t)gr * W + gc]);
      if (isPred) {
        v.x = sigmf(v.x); v.y = sigmf(v.y); v.z = sigmf(v.z); v.w = sigmf(v.w);
      }
      h4 hv;
      hv[0] = (_Float16)v.x; hv[1] = (_Float16)v.y;
      hv[2] = (_Float16)v.z; hv[3] = (_Float16)v.w;
      *(h4*)(buf0 + row * SW + 4 * g) = hv;
    }
  } else {
    for (int it = tid; it < SROWS * 24; it += NT) {
      int row = it / 24, g = it - row * 24;
      int gr = min(max(tr - 13 + row, 0), H - 1);
      int gc = tc - 16 + 4 * g;
      float4 v;
      v.x = img[base + (size_t)gr * W + min(max(gc + 0, 0), W - 1)];
      v.y = img[base + (size_t)gr * W + min(max(gc + 1, 0), W - 1)];
      v.z = img[base + (size_t)gr * W + min(max(gc + 2, 0), W - 1)];
      v.w = img[base + (size_t)gr * W + min(max(gc + 3, 0), W - 1)];
      if (isPred) {
        v.x = sigmf(v.x); v.y = sigmf(v.y); v.z = sigmf(v.z); v.w = sigmf(v.w);
      }
      h4 hv;
      hv[0] = (_Float16)v.x; hv[1] = (_Float16)v.y;
      hv[2] = (_Float16)v.z; hv[3] = (_Float16)v.w;
      *(h4*)(buf0 + row * SW + 4 * g) = hv;
    }
  }
  __syncthreads();

  const int ty = tid >> 2;  // 0..63: own tile row
  const int tg = tid & 3;   // 0..3 : own 16-col group
  const int rr = 13 + ty;
  const int ca = rr * SW + 16 + 16 * tg;

  // ---- Pass-invariant erode item addresses (516 items = 43 pairs x 12) ----
  // item it: rp = it/12, g = it%12, a = (2+2*rp)*SW + 8*g
  const int it1 = tid + 256;
  const int rp0 = tid / 12, g0 = tid - rp0 * 12;
  const int rp1 = it1 / 12, g1 = it1 - rp1 * 12;
  const int a0 = (2 + 2 * rp0) * SW + 8 * g0;
  const int a1 = (2 + 2 * rp1) * SW + 8 * g1;
  const int it2 = tid + 512;
  const int rp2 = it2 / 12, g2 = it2 - rp2 * 12;
  const int a2 = (2 + 2 * min(rp2, 42)) * SW + 8 * g2;  // clamped; gated below
  const bool has2 = (tid < 4);

  h8 skelE = (h8)(_Float16)0.0f;
  h8 skelF = (h8)(_Float16)0.0f;

#define PASS(S, D)                                                        \
  {                                                                       \
    h8 t0E = *(const h8*)(S + ca);                                        \
    h8 t0F = *(const h8*)(S + ca + 8);                                    \
    erode_item(S, D, a0);                                                 \
    erode_item(S, D, a1);                                                 \
    if (has2) erode_item(S, D, a2);                                       \
    __syncthreads();                                                      \
    const _Float16* pm = D + ca - SW;                                     \
    h8 aE = *(const h8*)(pm),          aF = *(const h8*)(pm + 8);         \
    h8 bE = *(const h8*)(pm + SW),     bF = *(const h8*)(pm + SW + 8);    \
    h8 cE = *(const h8*)(pm + 2 * SW), cF = *(const h8*)(pm + 2 * SW + 8);\
    _Float16 vl = hmax3(hi_half(pm - 2), hi_half(pm + SW - 2),            \
                        hi_half(pm + 2 * SW - 2));                        \
    _Float16 vr = hmax3(lo_half(pm + 16), lo_half(pm + SW + 16),          \
                        lo_half(pm + 2 * SW + 16));                       \
    h8 vmE = max3v(aE, bE, cE);                                           \
    h8 vmF = max3v(aF, bF, cF);                                           \
    h8 hE = max3v(shl1(vmE, vl), vmE, shr1(vmE, vmF[0]));                 \
    h8 hF = max3v(shl1(vmF, vmE[7]), vmF, shr1(vmF, vr));                 \
    h8 z = (h8)(_Float16)0.0f;                                            \
    h8 dE = __builtin_elementwise_max(t0E - hE, z);                       \
    h8 dF = __builtin_elementwise_max(t0F - hF, z);                       \
    skelE += __builtin_elementwise_max(dE - skelE * dE, z);               \
    skelF += __builtin_elementwise_max(dF - skelF * dF, z);               \
  }

#pragma unroll 1
  for (int k = 0; k < 5; ++k) {
    PASS(buf0, buf1)
    PASS(buf1, buf0)
  }
  PASS(buf0, buf1)
#undef PASS

  // ---- Products with the other image over own 16 px ----
  const float* orow = other + base + (size_t)(tr + ty) * W + tc + 16 * tg;
  float s0 = 0.0f, s1 = 0.0f;
#pragma unroll
  for (int q = 0; q < 4; ++q) {
    float4 o = ld4(orow + 4 * q);
    if (!isPred) {
      o.x = sigmf(o.x); o.y = sigmf(o.y); o.z = sigmf(o.z); o.w = sigmf(o.w);
    }
    float sk0, sk1, sk2, sk3;
    if (q < 2) {
      sk0 = (float)skelE[4 * q + 0]; sk1 = (float)skelE[4 * q + 1];
      sk2 = (float)skelE[4 * q + 2]; sk3 = (float)skelE[4 * q + 3];
    } else {
      sk0 = (float)skelF[4 * q - 8]; sk1 = (float)skelF[4 * q - 7];
      sk2 = (float)skelF[4 * q - 6]; sk3 = (float)skelF[4 * q - 5];
    }
    s0 += (sk0 + sk1) + (sk2 + sk3);
    s1 += (sk0 * o.x + sk1 * o.y) + (sk2 * o.z + sk3 * o.w);
  }

#pragma unroll
  for (int off = 32; off > 0; off >>= 1) {
    s0 += __shfl_down(s0, off, 64);
    s1 += __shfl_down(s1, off, 64);
  }
  const int wave = tid >> 6;
  if ((tid & 63) == 0) {
    rbuf[0][wave] = s0;
    rbuf[1][wave] = s1;
  }
  __syncthreads();
  if (tid == 0) {
    float t0s = 0.0f, t1s = 0.0f;
#pragma unroll
    for (int w = 0; w < NT / 64; ++w) {
      t0s += rbuf[0][w];
      t1s += rbuf[1][w];
    }
    const int bank = (int)(blockIdx.x & (NBANKS - 1));
    const int o2 = (isPred ? 0 : 2);
    atomicAdd(&sums[bank * BANK_STRIDE + o2], (double)t0s);
    atomicAdd(&sums[bank * BANK_STRIDE + o2 + 1], (double)t1s);
  }
}

__global__ void cl_finalize_kernel(const double* __restrict__ sums,
                                   float* __restrict__ out) {
  double s[4] = {0.0, 0.0, 0.0, 0.0};
  for (int b = 0; b < NBANKS; ++b)
    for (int j = 0; j < 4; ++j) s[j] += sums[b * BANK_STRIDE + j];
  double tprec = (s[1] + 1.0) / (s[0] + 1.0);
  double tsens = (s[3] + 1.0) / (s[2] + 1.0);
  double cl = 2.0 * tprec * tsens / (tprec + tsens + 1e-7);
  out[0] = (float)(1.0 - cl);
}

extern "C" void kernel_launch(void* const* d_in, const int* in_sizes, int n_in,
                              void* d_out, int out_size, void* d_ws,
                              size_t ws_size, hipStream_t stream) {
  const float* pred = (const float*)d_in[0];
  const float* target = (const float*)d_in[1];
  double* sums = (double*)d_ws;
  const int batch = in_sizes[0] / (H * W);  // 32

  hipMemsetAsync(d_ws, 0, NBANKS * BANK_STRIDE * sizeof(double), stream);
  dim3 grid(TPD * TPD, batch, 2);
  cl_skel_kernel<<<grid, NT, 0, stream>>>(pred, target, sums);
  cl_finalize_kernel<<<1, 1, 0, stream>>>(sums, (float*)d_out);
}